// Round 1
// baseline (91.748 us; speedup 1.0000x reference)
//
#include <hip/hip_runtime.h>
#include <hip/hip_bf16.h>

// SparseChannel2Spatial: N voxels, C=64 channels, F3=8 children/voxel,
// exactly K=4 active children per voxel -> M = N*K output rows.
// Output row r: voxel i = r/4, child j = (r%4)-th set slot in sub[i][0..7].
//   new_feats[r][0..7] = feats[i][j*8 .. j*8+7]
//   new_coords[r]      = [c0, 2*c1 + (j&1), 2*c2 + ((j>>1)&1), 2*c3 + ((j>>2)&1)]
// d_out (float32): [M*8 new_feats][M*4 new_coords-as-float].

__global__ __launch_bounds__(256) void sc2s_kernel(
    const float* __restrict__ feats,   // [N, 64]
    const int*   __restrict__ coords,  // [N, 4]
    const int*   __restrict__ sub,     // [N, 8]
    float* __restrict__ out_feats,     // [M, 8]
    float* __restrict__ out_coords,    // [M, 4] (float-converted ints)
    int M) {
  int r = blockIdx.x * blockDim.x + threadIdx.x;
  if (r >= M) return;
  int i = r >> 2;        // parent voxel
  int k = r & 3;         // which active child (0..3)

  // Load the 8-int sub row as two int4 (32B, aligned).
  const int4* s4 = reinterpret_cast<const int4*>(sub) + (size_t)i * 2;
  int4 a = s4[0];
  int4 b = s4[1];
  unsigned m = (unsigned)(a.x != 0)
             | ((unsigned)(a.y != 0) << 1)
             | ((unsigned)(a.z != 0) << 2)
             | ((unsigned)(a.w != 0) << 3)
             | ((unsigned)(b.x != 0) << 4)
             | ((unsigned)(b.y != 0) << 5)
             | ((unsigned)(b.z != 0) << 6)
             | ((unsigned)(b.w != 0) << 7);
  // Drop the k lowest set bits, then j = lowest remaining set bit.
  #pragma unroll
  for (int t = 0; t < 3; ++t) {
    if (t < k) m &= (m - 1);
  }
  int j = __ffs(m) - 1;

  // Gather the child's 8-float feature chunk (two float4, 32B aligned).
  const float4* f4 = reinterpret_cast<const float4*>(feats) + (size_t)i * 16 + (size_t)j * 2;
  float4 f0 = f4[0];
  float4 f1 = f4[1];
  float4* of = reinterpret_cast<float4*>(out_feats) + (size_t)r * 2;
  of[0] = f0;
  of[1] = f1;

  // Coords: component 0 unscaled, spatial components scaled by 2 + octant offset.
  int4 c = reinterpret_cast<const int4*>(coords)[i];
  float4 oc;
  oc.x = (float)c.x;
  oc.y = (float)(c.y * 2 + (j & 1));
  oc.z = (float)(c.z * 2 + ((j >> 1) & 1));
  oc.w = (float)(c.w * 2 + ((j >> 2) & 1));
  reinterpret_cast<float4*>(out_coords)[r] = oc;
}

extern "C" void kernel_launch(void* const* d_in, const int* in_sizes, int n_in,
                              void* d_out, int out_size, void* d_ws, size_t ws_size,
                              hipStream_t stream) {
  const float* feats  = (const float*)d_in[0];  // [N, 64] float32
  const int*   coords = (const int*)d_in[1];    // [N, 4] int32
  const int*   sub    = (const int*)d_in[2];    // [N, 8] int32

  // out_size = M*8 + M*4 = 12*M
  int M = out_size / 12;
  float* out_feats  = (float*)d_out;
  float* out_coords = (float*)d_out + (size_t)M * 8;

  int block = 256;
  int grid = (M + block - 1) / block;
  sc2s_kernel<<<grid, block, 0, stream>>>(feats, coords, sub, out_feats, out_coords, M);
}